// Round 1
// baseline (636.935 us; speedup 1.0000x reference)
//
#include <hip/hip_runtime.h>

typedef unsigned short u16;
typedef __attribute__((ext_vector_type(4))) u16 u16x4;
typedef __attribute__((ext_vector_type(8))) u16 u16x8;
typedef __attribute__((ext_vector_type(8))) short bf16x8;
typedef __attribute__((ext_vector_type(4))) float f32x4;

// Problem constants
#define BB 2
#define TT 2048
#define DD 768
#define NH 12
#define HDIM 64
#define NQKV 2304   // 3*DD
#define MM 4096     // BB*TT

__device__ __forceinline__ u16 f2bf(float f) {
  unsigned u = __float_as_uint(f);
  u += 0x7fffu + ((u >> 16) & 1u);
  return (u16)(u >> 16);
}
__device__ __forceinline__ float bf2f(u16 s) {
  return __uint_as_float(((unsigned)s) << 16);
}
__device__ __forceinline__ void async_load16(const void* g, void* l) {
  __builtin_amdgcn_global_load_lds((const __attribute__((address_space(1))) void*)g,
                                   (__attribute__((address_space(3))) void*)l, 16, 0, 0);
}

// ---------------- cast x (fp32 -> bf16) ----------------
__global__ __launch_bounds__(256) void castx(const float* __restrict__ x, u16* __restrict__ xb) {
  int i = blockIdx.x * 256 + threadIdx.x;           // one float4 per thread
  float4 v = ((const float4*)x)[i];
  u16x4 o = { f2bf(v.x), f2bf(v.y), f2bf(v.z), f2bf(v.w) };
  ((u16x4*)xb)[i] = o;
}

// ---------------- transpose + cast weights: W(K,N) fp32 -> WT(N,K) bf16 ----------------
__global__ __launch_bounds__(256) void wprep(const float* __restrict__ Wq, const float* __restrict__ Wk,
                                             const float* __restrict__ Wv, const float* __restrict__ Wo,
                                             u16* __restrict__ wqkvT, u16* __restrict__ woT) {
  __shared__ float tile[32][33];
  int z = blockIdx.z;
  const float* W = (z == 0) ? Wq : (z == 1) ? Wk : (z == 2) ? Wv : Wo;
  u16* dst = (z < 3) ? (wqkvT + (size_t)z * DD * DD) : woT;
  int k0 = blockIdx.x * 32, n0 = blockIdx.y * 32;
  int tx = threadIdx.x, ty = threadIdx.y;           // 32 x 8
#pragma unroll
  for (int j = 0; j < 4; ++j)
    tile[ty + j * 8][tx] = W[(size_t)(k0 + ty + j * 8) * DD + n0 + tx];
  __syncthreads();
#pragma unroll
  for (int j = 0; j < 4; ++j)
    dst[(size_t)(n0 + ty + j * 8) * DD + k0 + tx] = f2bf(tile[tx][ty + j * 8]);
}

// ---------------- g_idx / gpos LUT / fused qkv bias ----------------
__global__ __launch_bounds__(64) void prep_misc(const int* __restrict__ gm,
                                                const float* __restrict__ bq, const float* __restrict__ bk,
                                                const float* __restrict__ bv,
                                                int* __restrict__ gidx, int* __restrict__ gpos,
                                                float* __restrict__ biasqkv) {
  int lane = threadIdx.x;
  if (lane < 32) gidx[lane] = 0;
  for (int c = lane; c < TT; c += 64) gpos[c] = -1;
  int base = 0;
  for (int c0 = 0; c0 < TT; c0 += 64) {
    int mval = gm[c0 + lane];
    unsigned long long bal = __ballot(mval != 0);
    int pre = __popcll(bal & ((1ull << lane) - 1ull));
    if (mval && (base + pre) < 32) { gidx[base + pre] = c0 + lane; gpos[c0 + lane] = base + pre; }
    base += __popcll(bal);
  }
  for (int n = lane; n < NQKV; n += 64)
    biasqkv[n] = (n < 768) ? bq[n] : (n < 1536) ? bk[n - 768] : bv[n - 1536];
}

// ---------------- bf16 MFMA GEMM: C(M,N) = A(M,K) * BT(N,K)^T + bias ----------------
__global__ __launch_bounds__(256) void gemm_bt(const u16* __restrict__ A, const u16* __restrict__ BT,
                                               const float* __restrict__ bias, float* __restrict__ C,
                                               int Mdim, int Ndim, int Kd) {
  __shared__ __attribute__((aligned(16))) u16 As[128 * 64];
  __shared__ __attribute__((aligned(16))) u16 Bs[128 * 64];
  const int tid = threadIdx.x;
  const int wave = tid >> 6, lane = tid & 63;
  const int m0 = blockIdx.x * 128, n0 = blockIdx.y * 128;
  const int wm = (wave & 1) << 6, wn = (wave >> 1) << 6;
  const int lr = lane & 15, lk = lane >> 4;
  const int srow_b = lane >> 3;          // 0..7
  const int scol = (lane & 7) * 8;       // ushort offset within 128B row slice

  f32x4 acc[4][4] = {};

  const int kIters = Kd >> 6;
  for (int kt = 0; kt < kIters; ++kt) {
#pragma unroll
    for (int cc = 0; cc < 4; ++cc) {
      int c = wave * 4 + cc;
      int srow = c * 8 + srow_b;
      async_load16(A + (size_t)(m0 + srow) * Kd + (kt << 6) + scol, (void*)(As + c * 512));
      async_load16(BT + (size_t)(n0 + srow) * Kd + (kt << 6) + scol, (void*)(Bs + c * 512));
    }
    __syncthreads();
#pragma unroll
    for (int kc = 0; kc < 2; ++kc) {
      bf16x8 af[4], bfr[4];
#pragma unroll
      for (int i = 0; i < 4; ++i)
        af[i] = *(const bf16x8*)(As + (wm + i * 16 + lr) * 64 + kc * 32 + lk * 8);
#pragma unroll
      for (int j = 0; j < 4; ++j)
        bfr[j] = *(const bf16x8*)(Bs + (wn + j * 16 + lr) * 64 + kc * 32 + lk * 8);
#pragma unroll
      for (int i = 0; i < 4; ++i)
#pragma unroll
        for (int j = 0; j < 4; ++j)
          acc[i][j] = __builtin_amdgcn_mfma_f32_16x16x32_bf16(af[i], bfr[j], acc[i][j], 0, 0, 0);
    }
    __syncthreads();
  }

#pragma unroll
  for (int i = 0; i < 4; ++i) {
    const int row = m0 + wm + i * 16 + lk * 4;
#pragma unroll
    for (int j = 0; j < 4; ++j) {
      const int col = n0 + wn + j * 16 + lr;
      const float bs = bias[col];
#pragma unroll
      for (int r = 0; r < 4; ++r)
        C[(size_t)(row + r) * Ndim + col] = acc[i][j][r] + bs;
    }
  }
}

// ---------------- attention: one block = (b, h, 64 t-rows) ----------------
__global__ __launch_bounds__(256) void attn_kernel(const float* __restrict__ qkv,
                                                   const int* __restrict__ gidx,
                                                   const int* __restrict__ gpos,
                                                   u16* __restrict__ ctxb,
                                                   float* __restrict__ fattn) {
  // bf16 K/V tiles, padded rows (72 u16 = 144B: 16B-aligned, breaks 128B bank alias)
  __shared__ __attribute__((aligned(16))) u16 Kl[96 * 72];
  __shared__ __attribute__((aligned(16))) u16 Kg[32 * 72];
  __shared__ __attribute__((aligned(16))) u16 Vl[96 * 72];
  __shared__ __attribute__((aligned(16))) u16 Vg[32 * 72];
  __shared__ __attribute__((aligned(16))) float probs[64 * 68];
  __shared__ int gposs[TT];

  const int tid = threadIdx.x;
  const int blk = blockIdx.x;
  const int chunk = blk & 31;
  const int h = (blk >> 5) % NH;
  const int b = blk / 384;
  const int t0 = chunk << 6;

  // ---- phase 1: stage K/V (local window rows t0-16 .. t0+79, clamped; 32 global rows) ----
  {
    const int r = tid >> 4;
    const int c4 = (tid & 15) << 2;
#pragma unroll
    for (int it = 0; it < 6; ++it) {
      int rr = it * 16 + r;
      int t = t0 - 16 + rr;
      t = t < 0 ? 0 : (t > TT - 1 ? TT - 1 : t);
      const float* src = qkv + (size_t)(b * TT + t) * NQKV + h * HDIM;
      float4 kv = *(const float4*)(src + 768 + c4);
      float4 vv = *(const float4*)(src + 1536 + c4);
      u16x4 kb = { f2bf(kv.x), f2bf(kv.y), f2bf(kv.z), f2bf(kv.w) };
      u16x4 vb = { f2bf(vv.x), f2bf(vv.y), f2bf(vv.z), f2bf(vv.w) };
      *(u16x4*)(Kl + rr * 72 + c4) = kb;
      *(u16x4*)(Vl + rr * 72 + c4) = vb;
    }
#pragma unroll
    for (int it = 0; it < 2; ++it) {
      int rr = it * 16 + r;
      int t = gidx[rr];
      const float* src = qkv + (size_t)(b * TT + t) * NQKV + h * HDIM;
      float4 kv = *(const float4*)(src + 768 + c4);
      float4 vv = *(const float4*)(src + 1536 + c4);
      u16x4 kb = { f2bf(kv.x), f2bf(kv.y), f2bf(kv.z), f2bf(kv.w) };
      u16x4 vb = { f2bf(vv.x), f2bf(vv.y), f2bf(vv.z), f2bf(vv.w) };
      *(u16x4*)(Kg + rr * 72 + c4) = kb;
      *(u16x4*)(Vg + rr * 72 + c4) = vb;
    }
    for (int i = tid; i < TT; i += 256) gposs[i] = gpos[i];
  }
  __syncthreads();

  // ---- phase 2: scores + softmax. quad (4 threads) per t-row, scores strided by 4 ----
  const int tl = tid >> 2, sub = tid & 3;
  const int t = t0 + tl;
  const float* qp = qkv + (size_t)(b * TT + t) * NQKV + h * HDIM;
  float4 qr[16];
#pragma unroll
  for (int i = 0; i < 16; ++i) qr[i] = ((const float4*)qp)[i];

  float sc[17], pe[17];
  float mmax = -__builtin_inff();
#pragma unroll
  for (int i = 0; i < 17; ++i) {
    const int s = sub + (i << 2);
    const u16* kp;
    bool valid;
    if (s < 33) { kp = Kl + (tl + s) * 72; int j = t - 16 + s; valid = (j >= 0) && (j < TT); }
    else if (s < 65) { kp = Kg + (s - 33) * 72; valid = true; }
    else { kp = Kg; valid = false; }
    float d = 0.f;
#pragma unroll
    for (int i2 = 0; i2 < 8; ++i2) {
      u16x8 kv = *(const u16x8*)(kp + i2 * 8);
      float4 qa = qr[i2 * 2], qb = qr[i2 * 2 + 1];
      d += qa.x * bf2f(kv[0]) + qa.y * bf2f(kv[1]) + qa.z * bf2f(kv[2]) + qa.w * bf2f(kv[3]);
      d += qb.x * bf2f(kv[4]) + qb.y * bf2f(kv[5]) + qb.z * bf2f(kv[6]) + qb.w * bf2f(kv[7]);
    }
    sc[i] = valid ? d * 0.125f : -__builtin_inff();
    mmax = fmaxf(mmax, sc[i]);
  }
  mmax = fmaxf(mmax, __shfl_xor(mmax, 1));
  mmax = fmaxf(mmax, __shfl_xor(mmax, 2));
  float sum = 0.f;
#pragma unroll
  for (int i = 0; i < 17; ++i) { pe[i] = __expf(sc[i] - mmax); sum += pe[i]; }
  sum += __shfl_xor(sum, 1);
  sum += __shfl_xor(sum, 2);
  const float inv = 1.0f / sum;
#pragma unroll
  for (int i = 0; i < 17; ++i) {
    const int s = sub + (i << 2);
    if (s < 65) probs[tl * 68 + s] = pe[i] * inv;
  }
  __syncthreads();

  // ---- phase 3: ctx = sum_k p_k * V_k ; thread covers d in [sub*16, sub*16+16) ----
  float cacc[16];
#pragma unroll
  for (int i = 0; i < 16; ++i) cacc[i] = 0.f;
#pragma unroll 1
  for (int k = 0; k < 65; ++k) {
    const float pv = probs[tl * 68 + k];
    const u16* vp = (k < 33) ? (Vl + (tl + k) * 72) : (Vg + (k - 33) * 72);
    const u16* vq = vp + (sub << 4);
    u16x8 v0 = *(const u16x8*)(vq);
    u16x8 v1 = *(const u16x8*)(vq + 8);
#pragma unroll
    for (int e = 0; e < 8; ++e) { cacc[e] += pv * bf2f(v0[e]); cacc[8 + e] += pv * bf2f(v1[e]); }
  }
  {
    u16x8 cb0, cb1;
#pragma unroll
    for (int e = 0; e < 8; ++e) { cb0[e] = f2bf(cacc[e]); cb1[e] = f2bf(cacc[8 + e]); }
    u16* dst = ctxb + (size_t)(b * TT + t) * DD + h * HDIM + (sub << 4);
    *(u16x8*)dst = cb0;
    *(u16x8*)(dst + 8) = cb1;
  }

  // ---- phase 4: write full_attn rows (zeros fused with local/global values) ----
  float* fbase = fattn + (size_t)(b * NH + h) * TT * TT;
#pragma unroll 1
  for (int it = 0; it < 128; ++it) {
    int f = it * 256 + tid;
    int rl = f >> 9;
    int c4 = (f & 511) << 2;
    const float* pr = probs + rl * 68;
    int trow = t0 + rl;
    float vals[4];
#pragma unroll
    for (int e = 0; e < 4; ++e) {
      int c = c4 + e;
      float val = 0.f;
      int kk = c - trow + 16;
      if ((unsigned)kk < 33u) val = pr[kk];
      int g = gposs[c];
      if (g >= 0) val = pr[33 + g];
      vals[e] = val;
    }
    *(float4*)(fbase + (size_t)trow * TT + c4) = make_float4(vals[0], vals[1], vals[2], vals[3]);
  }
}

extern "C" void kernel_launch(void* const* d_in, const int* in_sizes, int n_in,
                              void* d_out, int out_size, void* d_ws, size_t ws_size,
                              hipStream_t stream) {
  const float* x  = (const float*)d_in[0];
  const int* gm   = (const int*)d_in[1];
  const float* Wq = (const float*)d_in[2];
  const float* bq = (const float*)d_in[3];
  const float* Wk = (const float*)d_in[4];
  const float* bk = (const float*)d_in[5];
  const float* Wv = (const float*)d_in[6];
  const float* bv = (const float*)d_in[7];
  const float* Wo = (const float*)d_in[8];
  const float* bo = (const float*)d_in[9];

  float* out = (float*)d_out;
  float* fattn = out + (size_t)BB * TT * DD;

  char* p = (char*)d_ws;
  u16* xb      = (u16*)p;  p += (size_t)MM * DD * 2;        // 6291456
  u16* wqkvT   = (u16*)p;  p += (size_t)NQKV * DD * 2;      // 3538944
  u16* woT     = (u16*)p;  p += (size_t)DD * DD * 2;        // 1179648
  float* biasq = (float*)p; p += (size_t)NQKV * 4;          // 9216
  int* gidx    = (int*)p;  p += 128;
  int* gpos    = (int*)p;  p += (size_t)TT * 4;             // 8192
  float* qkv   = (float*)p; p += (size_t)MM * NQKV * 4;     // 37748736
  u16* ctxb    = (u16*)p;  p += (size_t)MM * DD * 2;        // 6291456

  castx<<<MM * DD / 4 / 256, 256, 0, stream>>>(x, xb);
  wprep<<<dim3(24, 24, 4), dim3(32, 8), 0, stream>>>(Wq, Wk, Wv, Wo, wqkvT, woT);
  prep_misc<<<1, 64, 0, stream>>>(gm, bq, bk, bv, gidx, gpos, biasq);
  gemm_bt<<<dim3(MM / 128, NQKV / 128), 256, 0, stream>>>(xb, wqkvT, biasq, qkv, MM, NQKV, DD);
  attn_kernel<<<BB * NH * (TT / 64), 256, 0, stream>>>(qkv, gidx, gpos, ctxb, fattn);
  gemm_bt<<<dim3(MM / 128, DD / 128), 256, 0, stream>>>(ctxb, woT, bo, out, MM, DD, DD);
}

// Round 2
// 562.688 us; speedup vs baseline: 1.1319x; 1.1319x over previous
//
#include <hip/hip_runtime.h>

typedef unsigned short u16;
typedef __attribute__((ext_vector_type(4))) u16 u16x4;
typedef __attribute__((ext_vector_type(8))) u16 u16x8;
typedef __attribute__((ext_vector_type(8))) short bf16x8;
typedef __attribute__((ext_vector_type(4))) float f32x4;

// Problem constants
#define BB 2
#define TT 2048
#define DD 768
#define NH 12
#define HDIM 64
#define NQKV 2304   // 3*DD
#define MM 4096     // BB*TT

__device__ __forceinline__ u16 f2bf(float f) {
  unsigned u = __float_as_uint(f);
  u += 0x7fffu + ((u >> 16) & 1u);
  return (u16)(u >> 16);
}
__device__ __forceinline__ float bf2f(u16 s) {
  return __uint_as_float(((unsigned)s) << 16);
}
__device__ __forceinline__ void async_load16(const void* g, void* l) {
  __builtin_amdgcn_global_load_lds((const __attribute__((address_space(1))) void*)g,
                                   (__attribute__((address_space(3))) void*)l, 16, 0, 0);
}

// ---------------- zero-fill full_attn (pure streaming, fill-rate yardstick) ----------------
__global__ __launch_bounds__(256) void fill0(float4* __restrict__ p) {
  p[(size_t)blockIdx.x * 256 + threadIdx.x] = make_float4(0.f, 0.f, 0.f, 0.f);
}

// ---------------- cast x (fp32 -> bf16) ----------------
__global__ __launch_bounds__(256) void castx(const float* __restrict__ x, u16* __restrict__ xb) {
  int i = blockIdx.x * 256 + threadIdx.x;           // one float4 per thread
  float4 v = ((const float4*)x)[i];
  u16x4 o = { f2bf(v.x), f2bf(v.y), f2bf(v.z), f2bf(v.w) };
  ((u16x4*)xb)[i] = o;
}

// ---------------- transpose + cast weights: W(K,N) fp32 -> WT(N,K) bf16 ----------------
__global__ __launch_bounds__(256) void wprep(const float* __restrict__ Wq, const float* __restrict__ Wk,
                                             const float* __restrict__ Wv, const float* __restrict__ Wo,
                                             u16* __restrict__ wqkvT, u16* __restrict__ woT) {
  __shared__ float tile[32][33];
  int z = blockIdx.z;
  const float* W = (z == 0) ? Wq : (z == 1) ? Wk : (z == 2) ? Wv : Wo;
  u16* dst = (z < 3) ? (wqkvT + (size_t)z * DD * DD) : woT;
  int k0 = blockIdx.x * 32, n0 = blockIdx.y * 32;
  int tx = threadIdx.x, ty = threadIdx.y;           // 32 x 8
#pragma unroll
  for (int j = 0; j < 4; ++j)
    tile[ty + j * 8][tx] = W[(size_t)(k0 + ty + j * 8) * DD + n0 + tx];
  __syncthreads();
#pragma unroll
  for (int j = 0; j < 4; ++j)
    dst[(size_t)(n0 + ty + j * 8) * DD + k0 + tx] = f2bf(tile[tx][ty + j * 8]);
}

// ---------------- g_idx / gpos LUT / fused qkv bias ----------------
__global__ __launch_bounds__(256) void prep_misc(const int* __restrict__ gm,
                                                 const float* __restrict__ bq, const float* __restrict__ bk,
                                                 const float* __restrict__ bv,
                                                 int* __restrict__ gidx, int* __restrict__ gpos,
                                                 float* __restrict__ biasqkv) {
  int tid = threadIdx.x;
  if (tid < 32) gidx[tid] = 0;
  for (int c = tid; c < TT; c += 256) gpos[c] = -1;
  for (int n = tid; n < NQKV; n += 256)
    biasqkv[n] = (n < 768) ? bq[n] : (n < 1536) ? bk[n - 768] : bv[n - 1536];
  __syncthreads();
  if (tid < 64) {                                    // wave 0 only
    int lane = tid;
    int base = 0;
    for (int c0 = 0; c0 < TT; c0 += 64) {
      int mval = gm[c0 + lane];
      unsigned long long bal = __ballot(mval != 0);
      int pre = __popcll(bal & ((1ull << lane) - 1ull));
      if (mval && (base + pre) < 32) { gidx[base + pre] = c0 + lane; gpos[c0 + lane] = base + pre; }
      base += __popcll(bal);
      if (base >= 32) break;                         // first 32 found
    }
  }
}

// ---------------- bf16 MFMA GEMM: C(M,N) = A(M,K) * BT(N,K)^T + bias ----------------
template <int BM>
__global__ __launch_bounds__(256) void gemm_bt(const u16* __restrict__ A, const u16* __restrict__ BT,
                                               const float* __restrict__ bias, float* __restrict__ C,
                                               int Ndim, int Kd) {
  constexpr int NJ = (BM == 128) ? 4 : 2;            // 16-col tiles per wave
  constexpr int ACH = BM / 32;                       // A staging chunks per wave
  __shared__ __attribute__((aligned(16))) u16 As[BM * 64];
  __shared__ __attribute__((aligned(16))) u16 Bs[128 * 64];
  const int tid = threadIdx.x;
  const int wave = tid >> 6, lane = tid & 63;
  const int m0 = blockIdx.x * BM, n0 = blockIdx.y * 128;
  const int wm = (BM == 128) ? ((wave & 1) << 6) : 0;
  const int wn = (BM == 128) ? ((wave >> 1) << 6) : (wave << 5);
  const int lr = lane & 15, lk = lane >> 4;
  const int srow_b = lane >> 3;          // 0..7
  const int scol = (lane & 7) * 8;       // ushort offset within 128B row slice

  f32x4 acc[4][NJ] = {};

  const int kIters = Kd >> 6;
  for (int kt = 0; kt < kIters; ++kt) {
#pragma unroll
    for (int cc = 0; cc < ACH; ++cc) {
      int c = wave * ACH + cc;
      int srow = c * 8 + srow_b;
      async_load16(A + (size_t)(m0 + srow) * Kd + (kt << 6) + scol, (void*)(As + c * 512));
    }
#pragma unroll
    for (int cc = 0; cc < 4; ++cc) {
      int c = wave * 4 + cc;
      int srow = c * 8 + srow_b;
      async_load16(BT + (size_t)(n0 + srow) * Kd + (kt << 6) + scol, (void*)(Bs + c * 512));
    }
    __syncthreads();
#pragma unroll
    for (int kc = 0; kc < 2; ++kc) {
      bf16x8 af[4], bfr[NJ];
#pragma unroll
      for (int i = 0; i < 4; ++i)
        af[i] = *(const bf16x8*)(As + (wm + i * 16 + lr) * 64 + kc * 32 + lk * 8);
#pragma unroll
      for (int j = 0; j < NJ; ++j)
        bfr[j] = *(const bf16x8*)(Bs + (wn + j * 16 + lr) * 64 + kc * 32 + lk * 8);
#pragma unroll
      for (int i = 0; i < 4; ++i)
#pragma unroll
        for (int j = 0; j < NJ; ++j)
          acc[i][j] = __builtin_amdgcn_mfma_f32_16x16x32_bf16(af[i], bfr[j], acc[i][j], 0, 0, 0);
    }
    __syncthreads();
  }

#pragma unroll
  for (int i = 0; i < 4; ++i) {
    const int row = m0 + wm + i * 16 + lk * 4;
#pragma unroll
    for (int j = 0; j < NJ; ++j) {
      const int col = n0 + wn + j * 16 + lr;
      const float bs = bias[col];
#pragma unroll
      for (int r = 0; r < 4; ++r)
        C[(size_t)(row + r) * Ndim + col] = acc[i][j][r] + bs;
    }
  }
}

// ---------------- attention: one block = (b, h, 64 t-rows); fattn pre-zeroed ----------------
__global__ __launch_bounds__(256) void attn_kernel(const float* __restrict__ qkv,
                                                   const int* __restrict__ gidx,
                                                   const int* __restrict__ gpos,
                                                   u16* __restrict__ ctxb,
                                                   float* __restrict__ fattn) {
  // bf16 K/V tiles, padded rows (72 u16 = 144B: 16B-aligned, breaks 128B bank alias)
  __shared__ __attribute__((aligned(16))) u16 Kl[96 * 72];
  __shared__ __attribute__((aligned(16))) u16 Kg[32 * 72];
  __shared__ __attribute__((aligned(16))) u16 Vl[96 * 72];
  __shared__ __attribute__((aligned(16))) u16 Vg[32 * 72];
  __shared__ __attribute__((aligned(16))) float probs[64 * 68];
  __shared__ int wgpos[96];
  __shared__ int gidxs[32];

  const int tid = threadIdx.x;
  const int blk = blockIdx.x;
  const int chunk = blk & 31;
  const int h = (blk >> 5) % NH;
  const int b = blk / 384;
  const int t0 = chunk << 6;

  // ---- phase 1: stage K/V (local window rows t0-16 .. t0+79, clamped; 32 global rows) ----
  {
    const int r = tid >> 4;
    const int c4 = (tid & 15) << 2;
#pragma unroll
    for (int it = 0; it < 6; ++it) {
      int rr = it * 16 + r;
      int t = t0 - 16 + rr;
      t = t < 0 ? 0 : (t > TT - 1 ? TT - 1 : t);
      const float* src = qkv + (size_t)(b * TT + t) * NQKV + h * HDIM;
      float4 kv = *(const float4*)(src + 768 + c4);
      float4 vv = *(const float4*)(src + 1536 + c4);
      u16x4 kb = { f2bf(kv.x), f2bf(kv.y), f2bf(kv.z), f2bf(kv.w) };
      u16x4 vb = { f2bf(vv.x), f2bf(vv.y), f2bf(vv.z), f2bf(vv.w) };
      *(u16x4*)(Kl + rr * 72 + c4) = kb;
      *(u16x4*)(Vl + rr * 72 + c4) = vb;
    }
#pragma unroll
    for (int it = 0; it < 2; ++it) {
      int rr = it * 16 + r;
      int t = gidx[rr];
      const float* src = qkv + (size_t)(b * TT + t) * NQKV + h * HDIM;
      float4 kv = *(const float4*)(src + 768 + c4);
      float4 vv = *(const float4*)(src + 1536 + c4);
      u16x4 kb = { f2bf(kv.x), f2bf(kv.y), f2bf(kv.z), f2bf(kv.w) };
      u16x4 vb = { f2bf(vv.x), f2bf(vv.y), f2bf(vv.z), f2bf(vv.w) };
      *(u16x4*)(Kg + rr * 72 + c4) = kb;
      *(u16x4*)(Vg + rr * 72 + c4) = vb;
    }
    if (tid < 32) gidxs[tid] = gidx[tid];
    if (tid < 96) {
      int t = t0 - 16 + tid;
      wgpos[tid] = ((unsigned)t < TT) ? gpos[t] : -1;
    }
  }
  __syncthreads();

  // ---- phase 2: scores + softmax. quad (4 threads) per t-row, scores strided by 4 ----
  const int tl = tid >> 2, sub = tid & 3;
  const int t = t0 + tl;
  const float* qp = qkv + (size_t)(b * TT + t) * NQKV + h * HDIM;
  float4 qr[16];
#pragma unroll
  for (int i = 0; i < 16; ++i) qr[i] = ((const float4*)qp)[i];

  float sc[17];
  float mmax = -__builtin_inff();
#pragma unroll
  for (int i = 0; i < 17; ++i) {
    const int s = sub + (i << 2);
    const u16* kp;
    bool valid;
    if (s < 33) { kp = Kl + (tl + s) * 72; int j = t - 16 + s; valid = (j >= 0) && (j < TT); }
    else if (s < 65) { kp = Kg + (s - 33) * 72; valid = true; }
    else { kp = Kg; valid = false; }
    float d = 0.f;
#pragma unroll
    for (int i2 = 0; i2 < 8; ++i2) {
      u16x8 kv = *(const u16x8*)(kp + i2 * 8);
      float4 qa = qr[i2 * 2], qb = qr[i2 * 2 + 1];
      d += qa.x * bf2f(kv[0]) + qa.y * bf2f(kv[1]) + qa.z * bf2f(kv[2]) + qa.w * bf2f(kv[3]);
      d += qb.x * bf2f(kv[4]) + qb.y * bf2f(kv[5]) + qb.z * bf2f(kv[6]) + qb.w * bf2f(kv[7]);
    }
    sc[i] = valid ? d * 0.125f : -__builtin_inff();
    mmax = fmaxf(mmax, sc[i]);
  }
  mmax = fmaxf(mmax, __shfl_xor(mmax, 1));
  mmax = fmaxf(mmax, __shfl_xor(mmax, 2));
  float sum = 0.f;
#pragma unroll
  for (int i = 0; i < 17; ++i) { sc[i] = __expf(sc[i] - mmax); sum += sc[i]; }
  sum += __shfl_xor(sum, 1);
  sum += __shfl_xor(sum, 2);
  const float inv = 1.0f / sum;
#pragma unroll
  for (int i = 0; i < 17; ++i) {
    const int s = sub + (i << 2);
    sc[i] *= inv;
    if (s < 65) probs[tl * 68 + s] = sc[i];
  }
  __syncthreads();

  // ---- phase 3: ctx = sum_k p_k * V_k ; thread covers d in [sub*16, sub*16+16) ----
  float cacc[16];
#pragma unroll
  for (int i = 0; i < 16; ++i) cacc[i] = 0.f;
#pragma unroll 1
  for (int k = 0; k < 65; ++k) {
    const float pv = probs[tl * 68 + k];
    const u16* vp = (k < 33) ? (Vl + (tl + k) * 72) : (Vg + (k - 33) * 72);
    const u16* vq = vp + (sub << 4);
    u16x8 v0 = *(const u16x8*)(vq);
    u16x8 v1 = *(const u16x8*)(vq + 8);
#pragma unroll
    for (int e = 0; e < 8; ++e) { cacc[e] += pv * bf2f(v0[e]); cacc[8 + e] += pv * bf2f(v1[e]); }
  }
  {
    u16x8 cb0, cb1;
#pragma unroll
    for (int e = 0; e < 8; ++e) { cb0[e] = f2bf(cacc[e]); cb1[e] = f2bf(cacc[8 + e]); }
    u16* dst = ctxb + (size_t)(b * TT + t) * DD + h * HDIM + (sub << 4);
    *(u16x8*)dst = cb0;
    *(u16x8*)(dst + 8) = cb1;
  }

  // ---- phase 4: scatter nonzero attn values (fattn pre-zeroed by fill0) ----
  // band: add-semantics, but columns are distinct per row, so write; skip global cols
  // (reference .set(a_g) overrides band .add) — those get the global value below.
  float* frow = fattn + ((size_t)(b * NH + h) * TT + t) * TT;
#pragma unroll
  for (int i = 0; i < 17; ++i) {
    const int s = sub + (i << 2);
    const float p = sc[i];
    if (s < 33) {
      int c = t - 16 + s;
      if ((unsigned)c < TT && wgpos[tl + s] < 0) frow[c] = p;
    } else if (s < 65) {
      frow[gidxs[s - 33]] = p;
    }
  }
}

extern "C" void kernel_launch(void* const* d_in, const int* in_sizes, int n_in,
                              void* d_out, int out_size, void* d_ws, size_t ws_size,
                              hipStream_t stream) {
  const float* x  = (const float*)d_in[0];
  const int* gm   = (const int*)d_in[1];
  const float* Wq = (const float*)d_in[2];
  const float* bq = (const float*)d_in[3];
  const float* Wk = (const float*)d_in[4];
  const float* bk = (const float*)d_in[5];
  const float* Wv = (const float*)d_in[6];
  const float* bv = (const float*)d_in[7];
  const float* Wo = (const float*)d_in[8];
  const float* bo = (const float*)d_in[9];

  float* out = (float*)d_out;
  float* fattn = out + (size_t)BB * TT * DD;

  char* p = (char*)d_ws;
  u16* xb      = (u16*)p;  p += (size_t)MM * DD * 2;        // 6291456
  u16* wqkvT   = (u16*)p;  p += (size_t)NQKV * DD * 2;      // 3538944
  u16* woT     = (u16*)p;  p += (size_t)DD * DD * 2;        // 1179648
  float* biasq = (float*)p; p += (size_t)NQKV * 4;          // 9216
  int* gidx    = (int*)p;  p += 128;
  int* gpos    = (int*)p;  p += (size_t)TT * 4;             // 8192
  float* qkv   = (float*)p; p += (size_t)MM * NQKV * 4;     // 37748736
  u16* ctxb    = (u16*)p;  p += (size_t)MM * DD * 2;        // 6291456

  castx<<<MM * DD / 4 / 256, 256, 0, stream>>>(x, xb);
  wprep<<<dim3(24, 24, 4), dim3(32, 8), 0, stream>>>(Wq, Wk, Wv, Wo, wqkvT, woT);
  prep_misc<<<1, 256, 0, stream>>>(gm, bq, bk, bv, gidx, gpos, biasq);
  // zero full_attn: B*H*T*T floats = 25165824 float4s
  fill0<<<(size_t)BB * NH * TT * TT / 4 / 256, 256, 0, stream>>>((float4*)fattn);
  gemm_bt<128><<<dim3(MM / 128, NQKV / 128), 256, 0, stream>>>(xb, wqkvT, biasq, qkv, NQKV, DD);
  attn_kernel<<<BB * NH * (TT / 64), 256, 0, stream>>>(qkv, gidx, gpos, ctxb, fattn);
  gemm_bt<64><<<dim3(MM / 64, DD / 128), 256, 0, stream>>>(ctxb, woT, bo, out, DD, DD);
}

// Round 3
// 547.894 us; speedup vs baseline: 1.1625x; 1.0270x over previous
//
#include <hip/hip_runtime.h>

typedef unsigned short u16;
typedef __attribute__((ext_vector_type(4))) u16 u16x4;
typedef __attribute__((ext_vector_type(8))) u16 u16x8;
typedef __attribute__((ext_vector_type(8))) short bf16x8;
typedef __attribute__((ext_vector_type(4))) float f32x4;

// Problem constants
#define BB 2
#define TT 2048
#define DD 768
#define NH 12
#define HDIM 64
#define NQKV 2304   // 3*DD
#define MM 4096     // BB*TT

__device__ __forceinline__ u16 f2bf(float f) {
  unsigned u = __float_as_uint(f);
  u += 0x7fffu + ((u >> 16) & 1u);
  return (u16)(u >> 16);
}
__device__ __forceinline__ float bf2f(u16 s) {
  return __uint_as_float(((unsigned)s) << 16);
}
__device__ __forceinline__ void async_load16(const void* g, void* l) {
  __builtin_amdgcn_global_load_lds((const __attribute__((address_space(1))) void*)g,
                                   (__attribute__((address_space(3))) void*)l, 16, 0, 0);
}

// ---------------- cast x (fp32 -> bf16) ----------------
__global__ __launch_bounds__(256) void castx(const float* __restrict__ x, u16* __restrict__ xb) {
  int i = blockIdx.x * 256 + threadIdx.x;           // one float4 per thread
  float4 v = ((const float4*)x)[i];
  u16x4 o = { f2bf(v.x), f2bf(v.y), f2bf(v.z), f2bf(v.w) };
  ((u16x4*)xb)[i] = o;
}

// ---------------- transpose + cast weights: W(K,N) fp32 -> WT(N,K) bf16 ----------------
__global__ __launch_bounds__(256) void wprep(const float* __restrict__ Wq, const float* __restrict__ Wk,
                                             const float* __restrict__ Wv, const float* __restrict__ Wo,
                                             u16* __restrict__ wqkvT, u16* __restrict__ woT) {
  __shared__ float tile[32][33];
  int z = blockIdx.z;
  const float* W = (z == 0) ? Wq : (z == 1) ? Wk : (z == 2) ? Wv : Wo;
  u16* dst = (z < 3) ? (wqkvT + (size_t)z * DD * DD) : woT;
  int k0 = blockIdx.x * 32, n0 = blockIdx.y * 32;
  int tx = threadIdx.x, ty = threadIdx.y;           // 32 x 8
#pragma unroll
  for (int j = 0; j < 4; ++j)
    tile[ty + j * 8][tx] = W[(size_t)(k0 + ty + j * 8) * DD + n0 + tx];
  __syncthreads();
#pragma unroll
  for (int j = 0; j < 4; ++j)
    dst[(size_t)(n0 + ty + j * 8) * DD + k0 + tx] = f2bf(tile[tx][ty + j * 8]);
}

// ---------------- g_idx / gpos LUT / fused qkv bias ----------------
__global__ __launch_bounds__(256) void prep_misc(const int* __restrict__ gm,
                                                 const float* __restrict__ bq, const float* __restrict__ bk,
                                                 const float* __restrict__ bv,
                                                 int* __restrict__ gidx, int* __restrict__ gpos,
                                                 float* __restrict__ biasqkv) {
  int tid = threadIdx.x;
  if (tid < 32) gidx[tid] = 0;
  for (int c = tid; c < TT; c += 256) gpos[c] = -1;
  for (int n = tid; n < NQKV; n += 256)
    biasqkv[n] = (n < 768) ? bq[n] : (n < 1536) ? bk[n - 768] : bv[n - 1536];
  __syncthreads();
  if (tid < 64) {                                    // wave 0 only
    int lane = tid;
    int base = 0;
    for (int c0 = 0; c0 < TT; c0 += 64) {
      int mval = gm[c0 + lane];
      unsigned long long bal = __ballot(mval != 0);
      int pre = __popcll(bal & ((1ull << lane) - 1ull));
      if (mval && (base + pre) < 32) { gidx[base + pre] = c0 + lane; gpos[c0 + lane] = base + pre; }
      base += __popcll(bal);
      if (base >= 32) break;                         // first 32 found
    }
  }
}

// ---------------- bf16 MFMA GEMM: C(M,N) = A(M,K) * BT(N,K)^T + bias ----------------
template <int BM, bool OUTBF>
__global__ __launch_bounds__(256) void gemm_bt(const u16* __restrict__ A, const u16* __restrict__ BT,
                                               const float* __restrict__ bias, void* __restrict__ Cv,
                                               int Ndim, int Kd) {
  constexpr int NJ = (BM == 128) ? 4 : 2;            // 16-col tiles per wave
  constexpr int ACH = BM / 32;                       // A staging chunks per wave
  __shared__ __attribute__((aligned(16))) u16 As[BM * 64];
  __shared__ __attribute__((aligned(16))) u16 Bs[128 * 64];
  const int tid = threadIdx.x;
  const int wave = tid >> 6, lane = tid & 63;
  const int m0 = blockIdx.x * BM, n0 = blockIdx.y * 128;
  const int wm = (BM == 128) ? ((wave & 1) << 6) : 0;
  const int wn = (BM == 128) ? ((wave >> 1) << 6) : (wave << 5);
  const int lr = lane & 15, lk = lane >> 4;
  const int srow_b = lane >> 3;          // 0..7
  const int scol = (lane & 7) * 8;       // ushort offset within 128B row slice

  f32x4 acc[4][NJ] = {};

  const int kIters = Kd >> 6;
  for (int kt = 0; kt < kIters; ++kt) {
#pragma unroll
    for (int cc = 0; cc < ACH; ++cc) {
      int c = wave * ACH + cc;
      int srow = c * 8 + srow_b;
      async_load16(A + (size_t)(m0 + srow) * Kd + (kt << 6) + scol, (void*)(As + c * 512));
    }
#pragma unroll
    for (int cc = 0; cc < 4; ++cc) {
      int c = wave * 4 + cc;
      int srow = c * 8 + srow_b;
      async_load16(BT + (size_t)(n0 + srow) * Kd + (kt << 6) + scol, (void*)(Bs + c * 512));
    }
    __syncthreads();
#pragma unroll
    for (int kc = 0; kc < 2; ++kc) {
      bf16x8 af[4], bfr[NJ];
#pragma unroll
      for (int i = 0; i < 4; ++i)
        af[i] = *(const bf16x8*)(As + (wm + i * 16 + lr) * 64 + kc * 32 + lk * 8);
#pragma unroll
      for (int j = 0; j < NJ; ++j)
        bfr[j] = *(const bf16x8*)(Bs + (wn + j * 16 + lr) * 64 + kc * 32 + lk * 8);
#pragma unroll
      for (int i = 0; i < 4; ++i)
#pragma unroll
        for (int j = 0; j < NJ; ++j)
          acc[i][j] = __builtin_amdgcn_mfma_f32_16x16x32_bf16(af[i], bfr[j], acc[i][j], 0, 0, 0);
    }
    __syncthreads();
  }

#pragma unroll
  for (int i = 0; i < 4; ++i) {
    const int row = m0 + wm + i * 16 + lk * 4;
#pragma unroll
    for (int j = 0; j < NJ; ++j) {
      const int col = n0 + wn + j * 16 + lr;
      const float bs = bias[col];
#pragma unroll
      for (int r = 0; r < 4; ++r) {
        const float val = acc[i][j][r] + bs;
        if (OUTBF) ((u16*)Cv)[(size_t)(row + r) * Ndim + col] = f2bf(val);
        else       ((float*)Cv)[(size_t)(row + r) * Ndim + col] = val;
      }
    }
  }
}

// ---------------- attention: one block = (b, h, 64 t-rows); writes its full_attn rows ----------------
__global__ __launch_bounds__(256) void attn_kernel(const u16* __restrict__ qb,
                                                   const int* __restrict__ gidx,
                                                   const int* __restrict__ gpos,
                                                   u16* __restrict__ ctxb,
                                                   float* __restrict__ fattn) {
  // bf16 K/V tiles, padded rows (72 u16 = 144B: 16B-aligned, breaks 128B bank alias)
  __shared__ __attribute__((aligned(16))) u16 Kl[96 * 72];
  __shared__ __attribute__((aligned(16))) u16 Kg[32 * 72];
  __shared__ __attribute__((aligned(16))) u16 Vl[96 * 72];
  __shared__ __attribute__((aligned(16))) u16 Vg[32 * 72];
  __shared__ __attribute__((aligned(16))) float probs[64 * 68];
  __shared__ int wgpos[96];
  __shared__ int gidxs[32];

  const int tid = threadIdx.x;
  const int blk = blockIdx.x;
  const int chunk = blk & 31;
  const int h = (blk >> 5) % NH;
  const int b = blk / 384;
  const int t0 = chunk << 6;

  // ---- phase 1: stage bf16 K/V (pure 16B copies; local rows t0-16..t0+79 clamped; 32 global) ----
  {
    const int r = tid >> 3;                // 0..31 rows per pass
    const int c8 = (tid & 7) << 3;         // 8 bf16 per lane
#pragma unroll
    for (int it = 0; it < 3; ++it) {
      int rr = it * 32 + r;
      int t = t0 - 16 + rr;
      t = t < 0 ? 0 : (t > TT - 1 ? TT - 1 : t);
      const u16* src = qb + (size_t)(b * TT + t) * NQKV + h * HDIM + c8;
      *(u16x8*)(Kl + rr * 72 + c8) = *(const u16x8*)(src + 768);
      *(u16x8*)(Vl + rr * 72 + c8) = *(const u16x8*)(src + 1536);
    }
    {
      int t = gidx[r];
      const u16* src = qb + (size_t)(b * TT + t) * NQKV + h * HDIM + c8;
      *(u16x8*)(Kg + r * 72 + c8) = *(const u16x8*)(src + 768);
      *(u16x8*)(Vg + r * 72 + c8) = *(const u16x8*)(src + 1536);
    }
    if (tid < 32) gidxs[tid] = gidx[tid];
    if (tid < 96) {
      int t = t0 - 16 + tid;
      wgpos[tid] = ((unsigned)t < TT) ? gpos[t] : -1;
    }
  }
  __syncthreads();

  // ---- phase 2: scores + softmax. quad (4 threads) per t-row, scores strided by 4 ----
  const int tl = tid >> 2, sub = tid & 3;
  const int t = t0 + tl;
  const u16* qp = qb + (size_t)(b * TT + t) * NQKV + h * HDIM;
  float qv[64];
#pragma unroll
  for (int i = 0; i < 8; ++i) {
    u16x8 qq = *(const u16x8*)(qp + i * 8);
#pragma unroll
    for (int e = 0; e < 8; ++e) qv[i * 8 + e] = bf2f(qq[e]);
  }

  float sc[17];
  float mmax = -__builtin_inff();
#pragma unroll
  for (int i = 0; i < 17; ++i) {
    const int s = sub + (i << 2);
    const u16* kp;
    bool valid;
    if (s < 33) { kp = Kl + (tl + s) * 72; int j = t - 16 + s; valid = (j >= 0) && (j < TT); }
    else if (s < 65) { kp = Kg + (s - 33) * 72; valid = true; }
    else { kp = Kg; valid = false; }
    float d = 0.f;
#pragma unroll
    for (int i2 = 0; i2 < 8; ++i2) {
      u16x8 kv = *(const u16x8*)(kp + i2 * 8);
#pragma unroll
      for (int e = 0; e < 8; ++e) d += qv[i2 * 8 + e] * bf2f(kv[e]);
    }
    sc[i] = valid ? d * 0.125f : -__builtin_inff();
    mmax = fmaxf(mmax, sc[i]);
  }
  mmax = fmaxf(mmax, __shfl_xor(mmax, 1));
  mmax = fmaxf(mmax, __shfl_xor(mmax, 2));
  float sum = 0.f;
#pragma unroll
  for (int i = 0; i < 17; ++i) { sc[i] = __expf(sc[i] - mmax); sum += sc[i]; }
  sum += __shfl_xor(sum, 1);
  sum += __shfl_xor(sum, 2);
  const float inv = 1.0f / sum;
#pragma unroll
  for (int i = 0; i < 17; ++i) {
    const int s = sub + (i << 2);
    sc[i] *= inv;
    if (s < 65) probs[tl * 68 + s] = sc[i];
  }
  __syncthreads();

  // ---- phase 3: ctx = sum_k p_k * V_k ; thread covers d in [sub*16, sub*16+16) ----
  float cacc[16];
#pragma unroll
  for (int i = 0; i < 16; ++i) cacc[i] = 0.f;
#pragma unroll 1
  for (int k = 0; k < 65; ++k) {
    const float pv = probs[tl * 68 + k];
    const u16* vp = (k < 33) ? (Vl + (tl + k) * 72) : (Vg + (k - 33) * 72);
    const u16* vq = vp + (sub << 4);
    u16x8 v0 = *(const u16x8*)(vq);
    u16x8 v1 = *(const u16x8*)(vq + 8);
#pragma unroll
    for (int e = 0; e < 8; ++e) { cacc[e] += pv * bf2f(v0[e]); cacc[8 + e] += pv * bf2f(v1[e]); }
  }
  {
    u16x8 cb0, cb1;
#pragma unroll
    for (int e = 0; e < 8; ++e) { cb0[e] = f2bf(cacc[e]); cb1[e] = f2bf(cacc[8 + e]); }
    u16* dst = ctxb + (size_t)(b * TT + t) * DD + h * HDIM + (sub << 4);
    *(u16x8*)dst = cb0;
    *(u16x8*)(dst + 8) = cb1;
  }

  // ---- phase 4a: stream-write our 64 fattn rows, band values embedded, zeros elsewhere ----
  float* fbase = fattn + ((size_t)(b * NH + h) * TT + t0) * TT;
#pragma unroll 1
  for (int it = 0; it < 128; ++it) {
    int f = it * 256 + tid;
    int rl = f >> 9;                 // row 0..63 (2 waves per row)
    int c4 = (f & 511) << 2;         // col 0..2044
    int trow = t0 + rl;
    float4 v = make_float4(0.f, 0.f, 0.f, 0.f);
    int kk = c4 - trow + 16;         // band coord of first element, valid range [0,33)
    if (kk >= -3 && kk < 33) {       // float4 intersects band
      const float* pr = probs + rl * 68;
      float* vp = &v.x;
#pragma unroll
      for (int e = 0; e < 4; ++e) {
        int k2 = kk + e;
        if ((unsigned)k2 < 33u) vp[e] = pr[k2];
      }
    }
    *(float4*)(fbase + (size_t)rl * TT + c4) = v;
  }
  __syncthreads();                    // order 4a stores before 4b overwrites (same CU/L2)

  // ---- phase 4b: overwrite the 32 global columns (reference .set overrides band .add) ----
  {
    int rl = tid >> 2, g0 = (tid & 3) << 3;
    const float* pr = probs + rl * 68 + 33;
    float* frow = fbase + (size_t)rl * TT;
#pragma unroll
    for (int e = 0; e < 8; ++e) frow[gidxs[g0 + e]] = pr[g0 + e];
  }
}

extern "C" void kernel_launch(void* const* d_in, const int* in_sizes, int n_in,
                              void* d_out, int out_size, void* d_ws, size_t ws_size,
                              hipStream_t stream) {
  const float* x  = (const float*)d_in[0];
  const int* gm   = (const int*)d_in[1];
  const float* Wq = (const float*)d_in[2];
  const float* bq = (const float*)d_in[3];
  const float* Wk = (const float*)d_in[4];
  const float* bk = (const float*)d_in[5];
  const float* Wv = (const float*)d_in[6];
  const float* bv = (const float*)d_in[7];
  const float* Wo = (const float*)d_in[8];
  const float* bo = (const float*)d_in[9];

  float* out = (float*)d_out;
  float* fattn = out + (size_t)BB * TT * DD;

  char* p = (char*)d_ws;
  u16* xb      = (u16*)p;  p += (size_t)MM * DD * 2;        // 6291456
  u16* wqkvT   = (u16*)p;  p += (size_t)NQKV * DD * 2;      // 3538944
  u16* woT     = (u16*)p;  p += (size_t)DD * DD * 2;        // 1179648
  float* biasq = (float*)p; p += (size_t)NQKV * 4;          // 9216
  int* gidx    = (int*)p;  p += 128;
  int* gpos    = (int*)p;  p += (size_t)TT * 4;             // 8192
  u16* qkvb    = (u16*)p;  p += (size_t)MM * NQKV * 2;      // 18874368 (bf16 qkv)
  u16* ctxb    = (u16*)p;  p += (size_t)MM * DD * 2;        // 6291456

  castx<<<MM * DD / 4 / 256, 256, 0, stream>>>(x, xb);
  wprep<<<dim3(24, 24, 4), dim3(32, 8), 0, stream>>>(Wq, Wk, Wv, Wo, wqkvT, woT);
  prep_misc<<<1, 256, 0, stream>>>(gm, bq, bk, bv, gidx, gpos, biasq);
  gemm_bt<128, true><<<dim3(MM / 128, NQKV / 128), 256, 0, stream>>>(xb, wqkvT, biasq, qkvb, NQKV, DD);
  attn_kernel<<<BB * NH * (TT / 64), 256, 0, stream>>>(qkvb, gidx, gpos, ctxb, fattn);
  gemm_bt<64, false><<<dim3(MM / 64, DD / 128), 256, 0, stream>>>(ctxb, woT, bo, out, DD, DD);
}